// Round 10
// baseline (121.194 us; speedup 1.0000x reference)
//
#include <hip/hip_runtime.h>
#include <hip/hip_bf16.h>

// MHA layer B=2, S=2048, DM=1024, H=16, DK=DV=64 on gfx950.
// conv fp32->bf16 -> weight transposes -> 3 proj GEMMs (m97 structure) ->
// flash attention kv-SPLIT (grid 1024, 32KB LDS, 4 blocks/CU; no-max log2 softmax
// makes halves pure sums; per-(half,q,h) partial l) -> combine -> out GEMM.

using bf16 = __hip_bfloat16;
typedef __attribute__((ext_vector_type(4))) float f32x4;
typedef __attribute__((ext_vector_type(8))) short bf16x8;

__device__ __forceinline__ void gload_lds16(const void* gsrc, void* ldst) {
    __builtin_amdgcn_global_load_lds(
        (const __attribute__((address_space(1))) void*)gsrc,
        (__attribute__((address_space(3))) void*)ldst,
        16, 0, 0);
}

__device__ __forceinline__ float fexp2(float x) {
    float r; asm("v_exp_f32 %0, %1" : "=v"(r) : "v"(x)); return r;
}

__device__ __forceinline__ unsigned cvtpk(float a, float b) {
    unsigned d; asm("v_cvt_pk_bf16_f32 %0, %1, %2" : "=v"(d) : "v"(a), "v"(b));
    return d;
}

__device__ __forceinline__ void pls32(unsigned &a, unsigned &b) {
    asm("v_permlane32_swap_b32 %0, %1" : "+v"(a), "+v"(b));
}
__device__ __forceinline__ void pls16(unsigned &a, unsigned &b) {
    asm("v_permlane16_swap_b32 %0, %1" : "+v"(a), "+v"(b));
}

__device__ __forceinline__ unsigned pack2bf(float a, float b) {
    unsigned short ua = __builtin_bit_cast(unsigned short, __float2bfloat16(a));
    unsigned short ub = __builtin_bit_cast(unsigned short, __float2bfloat16(b));
    return (unsigned)ua | ((unsigned)ub << 16);
}

__device__ __forceinline__ float bfu(unsigned lo16) {
    return __builtin_bit_cast(float, lo16 << 16);
}

// ---------------- fp32 -> bf16, three tensors (z) ----------------
__global__ void conv3_kernel(const float* __restrict__ X0, const float* __restrict__ X1,
                             const float* __restrict__ X2,
                             bf16* __restrict__ O0, bf16* __restrict__ O1, bf16* __restrict__ O2,
                             int n4) {
    int z = blockIdx.z;
    const float* in = z == 0 ? X0 : (z == 1 ? X1 : X2);
    bf16* out = z == 0 ? O0 : (z == 1 ? O1 : O2);
    int idx = blockIdx.x * blockDim.x + threadIdx.x;
    int stride = gridDim.x * blockDim.x;
    for (int i = idx; i < n4; i += stride) {
        float4 v = reinterpret_cast<const float4*>(in)[i];
        reinterpret_cast<uint2*>(out)[i] = make_uint2(pack2bf(v.x, v.y), pack2bf(v.z, v.w));
    }
}

// ---------------- 1024x1024 fp32 -> bf16 transpose, four weights (z) ----------------
__global__ void transpose4_kernel(const float* __restrict__ W0, const float* __restrict__ W1,
                                  const float* __restrict__ W2, const float* __restrict__ W3,
                                  bf16* __restrict__ T0, bf16* __restrict__ T1,
                                  bf16* __restrict__ T2, bf16* __restrict__ T3) {
    int z = blockIdx.z;
    const float* W = z == 0 ? W0 : (z == 1 ? W1 : (z == 2 ? W2 : W3));
    bf16* WT = z == 0 ? T0 : (z == 1 ? T1 : (z == 2 ? T2 : T3));
    __shared__ float t[32][33];
    int bx = blockIdx.x * 32, by = blockIdx.y * 32;
    int x = threadIdx.x, y = threadIdx.y;
    #pragma unroll
    for (int i = 0; i < 4; ++i)
        t[y + 8*i][x] = W[(size_t)(by + y + 8*i) * 1024 + bx + x];
    __syncthreads();
    #pragma unroll
    for (int i = 0; i < 4; ++i)
        WT[(size_t)(bx + y + 8*i) * 1024 + by + x] = __float2bfloat16(t[x][y + 8*i]);
}

// ---------------- GEMM: C[4096,NTOT] = A[4096,1024] @ BT^T + bias ----------------
// m97 structure: 128xNTILE tile, BK=64, single-buffered LDS, global_load_lds w16,
// XOR-swizzled rows via pre-swizzled global src, two barriers per K-step.
// mode = mode_base+z: 0 bf16 out *log2e/sqrt2 | 1 bf16 | 2 bf16 -> Vt[b][h][dv][s] | 3 fp32
template<int NTILE>
__global__ __launch_bounds__(256, 3)
void gemm_bt(const bf16* __restrict__ A0, const bf16* __restrict__ A1, const bf16* __restrict__ A2,
             const bf16* __restrict__ B0, const bf16* __restrict__ B1, const bf16* __restrict__ B2,
             const float* __restrict__ bi0, const float* __restrict__ bi1, const float* __restrict__ bi2,
             void* __restrict__ O0, void* __restrict__ O1, void* __restrict__ O2,
             int mode_base)
{
    const int f = blockIdx.x;
    int x, y, z;
    if (NTILE == 128) {
        const int s = f >> 3;
        y = s & 7;
        const int t = (f & 7) + 8 * (s >> 3);
        x = t & 31; z = t >> 5;
    } else {
        const int s = f >> 3;
        y = s & 15;
        x = (f & 7) + 8 * (s >> 4);
        z = 0;
    }
    const bf16* A  = z == 0 ? A0 : (z == 1 ? A1 : A2);
    const bf16* BT = z == 0 ? B0 : (z == 1 ? B1 : B2);
    const float* bias = z == 0 ? bi0 : (z == 1 ? bi1 : bi2);
    void* Cout = z == 0 ? O0 : (z == 1 ? O1 : O2);
    const int mode = mode_base + z;

    constexpr int MF = (NTILE == 128) ? 4 : 2;
    __shared__ __align__(16) char Abuf[16384];
    __shared__ __align__(16) char Bbuf[NTILE * 128];
    const int tid = threadIdx.x;
    const int wave = tid >> 6, lane = tid & 63;
    const int g = lane >> 4, ln = lane & 15;
    const int m0 = x * 128, n0 = y * NTILE;
    const int wm = (NTILE == 128) ? (wave >> 1) * 64 : wave * 32;
    const int wn = (NTILE == 128) ? (wave & 1) * 64 : 0;
    const int lnsw = (ln & 7) << 4;

    f32x4 acc[MF][4] = {};

    for (int k0 = 0; k0 < 1024; k0 += 64) {
        __syncthreads();
        #pragma unroll
        for (int rd = 0; rd < 4; ++rd) {
            int row = rd * 32 + (tid >> 3);
            int src = ((tid & 7) * 16) ^ (((tid >> 3) & 7) << 4);
            gload_lds16((const char*)(A + (size_t)(m0 + row) * 1024 + k0) + src,
                        Abuf + rd * 4096 + tid * 16);
        }
        #pragma unroll
        for (int rd = 0; rd < NTILE / 32; ++rd) {
            int row = rd * 32 + (tid >> 3);
            int src = ((tid & 7) * 16) ^ (((tid >> 3) & 7) << 4);
            gload_lds16((const char*)(BT + (size_t)(n0 + row) * 1024 + k0) + src,
                        Bbuf + rd * 4096 + tid * 16);
        }
        __syncthreads();
        #pragma unroll
        for (int kk = 0; kk < 2; ++kk) {
            bf16x8 af[MF], bfr[4];
            #pragma unroll
            for (int mf = 0; mf < MF; ++mf)
                af[mf] = *(const bf16x8*)&Abuf[(wm + mf*16 + ln) * 128 + ((kk*64 + g*16) ^ lnsw)];
            #pragma unroll
            for (int nf = 0; nf < 4; ++nf)
                bfr[nf] = *(const bf16x8*)&Bbuf[(wn + nf*16 + ln) * 128 + ((kk*64 + g*16) ^ lnsw)];
            #pragma unroll
            for (int mf = 0; mf < MF; ++mf)
                #pragma unroll
                for (int nf = 0; nf < 4; ++nf)
                    acc[mf][nf] = __builtin_amdgcn_mfma_f32_16x16x32_bf16(af[mf], bfr[nf], acc[mf][nf], 0, 0, 0);
        }
    }

    const float scl = (mode == 0) ? (0.70710678118654752f * 1.44269504088896340f) : 1.0f;
    #pragma unroll
    for (int mf = 0; mf < MF; ++mf) {
        #pragma unroll
        for (int nf = 0; nf < 4; ++nf) {
            int col = n0 + wn + nf*16 + ln;
            float bv = bias[col];
            #pragma unroll
            for (int r = 0; r < 4; ++r) {
                int row = m0 + wm + mf*16 + g*4 + r;
                float v = (acc[mf][nf][r] + bv) * scl;
                if (mode == 0 || mode == 1) {
                    ((bf16*)Cout)[(size_t)row * 1024 + col] = __float2bfloat16(v);
                } else if (mode == 2) {
                    int b = row >> 11, ss = row & 2047;
                    int hh = col >> 6, dv = col & 63;
                    ((bf16*)Cout)[(((size_t)(b*16 + hh) * 64 + dv) << 11) + ss] = __float2bfloat16(v);
                } else {
                    ((float*)Cout)[(size_t)row * 1024 + col] = v;
                }
            }
        }
    }
}

// ---------------- flash attention, kv-split ----------------
// qh: [B*S][1024] bf16 pre-scaled by log2e/sqrt(2); kh: [B*S][1024] bf16;
// vt: [B][H][64][2048] bf16.  Block = (bh, i, half): 128 q rows, kv in
// [half*1024, half*1024+1024), 16 tiles of 64 kv, double-buffered 32KB LDS.
// Writes UNNORMALIZED partial O (bf16) and partial l per (half, row, head).
// Grid 1024 XCD-grouped: f = (bh&7) + 8*(j + 32*(bh>>3)), j = i*2+half.
__global__ __launch_bounds__(256, 4)
void attn_kernel(const bf16* __restrict__ qh, const bf16* __restrict__ kh,
                 const bf16* __restrict__ vt, bf16* __restrict__ Opart,
                 float* __restrict__ lpart)
{
    __shared__ __align__(16) bf16 Kls[2][64 * 64];
    __shared__ __align__(16) bf16 Vls[2][64 * 64];
    const int f = blockIdx.x;
    const int xcd = f & 7, r = f >> 3, j = r & 31, ghi = r >> 5;
    const int bh = xcd + 8 * ghi;
    const int b = bh >> 4, h = bh & 15;
    const int i = j >> 1, half = j & 1;
    const int q0 = i * 128;
    const int kvbase = half * 1024;

    const int tid = threadIdx.x;
    const int wave = tid >> 6, lane = tid & 63;
    const int g = lane >> 4, ln = lane & 15;
    const int srow = lane >> 3;
    const int scol = ((lane & 7) * 16) ^ ((srow & 7) << 4);
    const int lnsw = (ln & 7) << 4;

    const bf16* kbase = kh + (size_t)(b * 2048) * 1024 + h * 64;
    const bf16* vbase = vt + (size_t)bh * 64 * 2048;

    bf16x8 qf[2][2];
    #pragma unroll
    for (int nf = 0; nf < 2; ++nf) {
        const bf16* qrow = qh + (size_t)(b*2048 + q0 + wave*32 + nf*16 + ln) * 1024 + h*64;
        qf[nf][0] = *(const bf16x8*)(qrow + g*8);
        qf[nf][1] = *(const bf16x8*)(qrow + 32 + g*8);
    }

    // stage one 64-kv tile (K: [64][128B], V: [64 dv][128B], both row-swizzled)
    auto stageKV = [&](int kv0, int buf) {
        #pragma unroll
        for (int c2 = 0; c2 < 2; ++c2) {
            int c = wave * 2 + c2;
            int row = c * 8 + srow;
            gload_lds16((const char*)(kbase + (size_t)(kv0 + row) * 1024) + scol,
                        (char*)&Kls[buf][0] + c * 1024);
            gload_lds16((const char*)(vbase + (size_t)row * 2048 + kv0) + scol,
                        (char*)&Vls[buf][0] + c * 1024);
        }
    };

    stageKV(kvbase, 0);

    f32x4 oacc[4][2] = {};
    f32x4 lacc[2] = {};
    union PU { unsigned u[4]; bf16x8 v; };
    PU ones;
    ones.u[0] = ones.u[1] = ones.u[2] = ones.u[3] = 0x3F803F80u;  // bf16 1.0 x2

    for (int t = 0; t < 16; ++t) {
        const int cur = t & 1;
        if (t < 15) {
            stageKV(kvbase + (t + 1) * 64, cur ^ 1);
            asm volatile("s_waitcnt vmcnt(4)\n\ts_barrier" ::: "memory");
        } else {
            asm volatile("s_waitcnt vmcnt(0)\n\ts_barrier" ::: "memory");
        }
        __builtin_amdgcn_sched_barrier(0);

        const char* Kc = (const char*)&Kls[cur][0];
        const char* Vc = (const char*)&Vls[cur][0];

        // S^T = K * Q^T (row = kv local, col = q)
        f32x4 sac[4][2] = {};
        __builtin_amdgcn_s_setprio(1);
        #pragma unroll
        for (int kk = 0; kk < 2; ++kk) {
            bf16x8 kf[4];
            #pragma unroll
            for (int mf = 0; mf < 4; ++mf)
                kf[mf] = *(const bf16x8*)(Kc + (mf*16 + ln) * 128 + ((kk*64 + g*16) ^ lnsw));
            #pragma unroll
            for (int mf = 0; mf < 4; ++mf)
                #pragma unroll
                for (int nf = 0; nf < 2; ++nf)
                    sac[mf][nf] = __builtin_amdgcn_mfma_f32_16x16x32_bf16(kf[mf], qf[nf][kk], sac[mf][nf], 0, 0, 0);
        }
        __builtin_amdgcn_s_setprio(0);

        // P = exp2(s); pack; permlane butterfly -> B-fragments
        PU pf[2][2];
        #pragma unroll
        for (int nf = 0; nf < 2; ++nf) {
            unsigned w[4][2];
            #pragma unroll
            for (int mf = 0; mf < 4; ++mf) {
                float e0 = fexp2(sac[mf][nf][0]);
                float e1 = fexp2(sac[mf][nf][1]);
                float e2 = fexp2(sac[mf][nf][2]);
                float e3 = fexp2(sac[mf][nf][3]);
                w[mf][0] = cvtpk(e0, e1);
                w[mf][1] = cvtpk(e2, e3);
            }
            #pragma unroll
            for (int kk = 0; kk < 2; ++kk) {
                #pragma unroll
                for (int rp = 0; rp < 2; ++rp) {
                    unsigned a = w[2*kk][rp], bb = w[2*kk + 1][rp];
                    pls32(a, bb);
                    pls16(a, bb);
                    pf[nf][kk].u[rp] = a;
                    pf[nf][kk].u[2 + rp] = bb;
                }
            }
        }

        // O^T += V^T * P ; l += ones * P
        __builtin_amdgcn_s_setprio(1);
        #pragma unroll
        for (int kk = 0; kk < 2; ++kk) {
            bf16x8 vf[4];
            #pragma unroll
            for (int mf = 0; mf < 4; ++mf)
                vf[mf] = *(const bf16x8*)(Vc + (mf*16 + ln) * 128 + ((kk*64 + g*16) ^ lnsw));
            #pragma unroll
            for (int nf = 0; nf < 2; ++nf)
                lacc[nf] = __builtin_amdgcn_mfma_f32_16x16x32_bf16(ones.v, pf[nf][kk].v, lacc[nf], 0, 0, 0);
            #pragma unroll
            for (int mf = 0; mf < 4; ++mf)
                #pragma unroll
                for (int nf = 0; nf < 2; ++nf)
                    oacc[mf][nf] = __builtin_amdgcn_mfma_f32_16x16x32_bf16(vf[mf], pf[nf][kk].v, oacc[mf][nf], 0, 0, 0);
        }
        __builtin_amdgcn_s_setprio(0);
        __builtin_amdgcn_sched_barrier(0);
        asm volatile("s_barrier" ::: "memory");
    }

    // epilogue: write UNNORMALIZED partial O (bf16) and per-(row, head) partial l
    bf16* Oh = Opart + (size_t)half * 4096 * 1024;
    float* lh = lpart + (size_t)half * 4096 * 16;
    #pragma unroll
    for (int nf = 0; nf < 2; ++nf) {
        int q = q0 + wave*32 + nf*16 + ln;
        int row = b*2048 + q;
        if (g == 0) lh[row * 16 + h] = lacc[nf][0];
        bf16* orow = Oh + (size_t)row * 1024 + h * 64;
        #pragma unroll
        for (int mf = 0; mf < 4; ++mf) {
            *(uint2*)(orow + mf*16 + g*4) = make_uint2(
                pack2bf(oacc[mf][nf][0], oacc[mf][nf][1]),
                pack2bf(oacc[mf][nf][2], oacc[mf][nf][3]));
        }
    }
}

// ---------------- combine partials: aout = (O0+O1)/(l0+l1) per head, bf16 ----------------
__global__ void combine_kernel(const unsigned short* __restrict__ Op,
                               const float* __restrict__ lpart,
                               bf16* __restrict__ aout)
{
    int idx = blockIdx.x * blockDim.x + threadIdx.x;   // 4096*128 items of 8 elems
    if (idx >= 4096 * 128) return;
    int q = idx >> 7, c = idx & 127;
    int h = c >> 3;                                    // 8 elems all within head h
    float inv = 1.0f / (lpart[q * 16 + h] + lpart[65536 + q * 16 + h]);
    const uint4 a = *(const uint4*)(Op + (size_t)q * 1024 + c * 8);
    const uint4 b = *(const uint4*)(Op + (size_t)(4096 + q) * 1024 + c * 8);
    unsigned o[4];
    const unsigned* ap = &a.x;
    const unsigned* bp = &b.x;
    #pragma unroll
    for (int w = 0; w < 4; ++w) {
        float lo = bfu(ap[w] & 0xffffu) + bfu(bp[w] & 0xffffu);
        float hi = __builtin_bit_cast(float, ap[w] & 0xffff0000u)
                 + __builtin_bit_cast(float, bp[w] & 0xffff0000u);
        o[w] = pack2bf(lo * inv, hi * inv);
    }
    *(uint4*)(aout + (size_t)q * 1024 + c * 8) = make_uint4(o[0], o[1], o[2], o[3]);
}

// ---------------- host ----------------
extern "C" void kernel_launch(void* const* d_in, const int* in_sizes, int n_in,
                              void* d_out, int out_size, void* d_ws, size_t ws_size,
                              hipStream_t stream)
{
    const float* Q  = (const float*)d_in[0];
    const float* K  = (const float*)d_in[1];
    const float* V  = (const float*)d_in[2];
    const float* Wq = (const float*)d_in[3];
    const float* bq = (const float*)d_in[4];
    const float* Wk = (const float*)d_in[5];
    const float* bk = (const float*)d_in[6];
    const float* Wv = (const float*)d_in[7];
    const float* bv = (const float*)d_in[8];
    const float* Wo = (const float*)d_in[9];
    const float* bo = (const float*)d_in[10];

    char* ws = (char*)d_ws;
    const size_t MB = 1024 * 1024;
    // phase 1 (conv+proj): Qbf 0-8, Kbf 8-16, Vbf 16-24, weights 24-32,
    //                      qhp 32-40, khp 40-48, vtp 48-56
    // phase 2 (attn):      Opart 0-16 (aliases Qbf/Kbf, dead), lpart 16-16.5 (Vbf, dead)
    // phase 3 (combine):   aout 17-25 (aliases Vbf tail + WqT, both dead)
    bf16* Qbf   = (bf16*)(ws + 0);
    bf16* Kbf   = (bf16*)(ws + 8*MB);
    bf16* Vbf   = (bf16*)(ws + 16*MB);
    bf16* WqT   = (bf16*)(ws + 24*MB);
    bf16* WkT   = (bf16*)(ws + 26*MB);
    bf16* WvT   = (bf16*)(ws + 28*MB);
    bf16* WoT   = (bf16*)(ws + 30*MB);
    bf16* qhp   = (bf16*)(ws + 32*MB);
    bf16* khp   = (bf16*)(ws + 40*MB);
    bf16* vtp   = (bf16*)(ws + 48*MB);
    bf16* Opart = (bf16*)(ws + 0);
    float* lpart = (float*)(ws + 16*MB);   // [2][4096][16] f32 = 512 KB
    bf16* aout  = (bf16*)(ws + 17*MB);

    const int n4 = (2 * 2048 * 1024) / 4;
    conv3_kernel<<<dim3(512, 1, 3), 256, 0, stream>>>(Q, K, V, Qbf, Kbf, Vbf, n4);

    transpose4_kernel<<<dim3(32, 32, 4), dim3(32, 8), 0, stream>>>(Wq, Wk, Wv, Wo, WqT, WkT, WvT, WoT);

    gemm_bt<128><<<768, 256, 0, stream>>>(Qbf, Kbf, Vbf, WqT, WkT, WvT,
                                          bq, bk, bv, qhp, khp, vtp, 0);

    attn_kernel<<<1024, 256, 0, stream>>>(qhp, khp, vtp, Opart, lpart);

    combine_kernel<<<2048, 256, 0, stream>>>((const unsigned short*)Opart, lpart, aout);

    gemm_bt<64><<<512, 256, 0, stream>>>(aout, aout, aout, WoT, WoT, WoT,
                                         bo, bo, bo, d_out, d_out, d_out, 3);
}

// Round 11
// 117.188 us; speedup vs baseline: 1.0342x; 1.0342x over previous
//
#include <hip/hip_runtime.h>
#include <hip/hip_bf16.h>

// MHA layer B=2, S=2048, DM=1024, H=16, DK=DV=64 on gfx950.
// conv fp32->bf16 -> weight transposes -> 3 proj GEMMs (m97 structure) ->
// flash attention (software-pipelined: QK(t) overlaps SM/PV(t-1); K dbuf, V tribuf)
// -> out GEMM (128x64 tiles). No kv-split (r10 showed it was net-negative).

using bf16 = __hip_bfloat16;
typedef __attribute__((ext_vector_type(4))) float f32x4;
typedef __attribute__((ext_vector_type(8))) short bf16x8;

__device__ __forceinline__ void gload_lds16(const void* gsrc, void* ldst) {
    __builtin_amdgcn_global_load_lds(
        (const __attribute__((address_space(1))) void*)gsrc,
        (__attribute__((address_space(3))) void*)ldst,
        16, 0, 0);
}

__device__ __forceinline__ float fexp2(float x) {
    float r; asm("v_exp_f32 %0, %1" : "=v"(r) : "v"(x)); return r;
}

__device__ __forceinline__ unsigned cvtpk(float a, float b) {
    unsigned d; asm("v_cvt_pk_bf16_f32 %0, %1, %2" : "=v"(d) : "v"(a), "v"(b));
    return d;
}

__device__ __forceinline__ void pls32(unsigned &a, unsigned &b) {
    asm("v_permlane32_swap_b32 %0, %1" : "+v"(a), "+v"(b));
}
__device__ __forceinline__ void pls16(unsigned &a, unsigned &b) {
    asm("v_permlane16_swap_b32 %0, %1" : "+v"(a), "+v"(b));
}

__device__ __forceinline__ unsigned pack2bf(float a, float b) {
    unsigned short ua = __builtin_bit_cast(unsigned short, __float2bfloat16(a));
    unsigned short ub = __builtin_bit_cast(unsigned short, __float2bfloat16(b));
    return (unsigned)ua | ((unsigned)ub << 16);
}

// ---------------- fp32 -> bf16, three tensors (z) ----------------
__global__ void conv3_kernel(const float* __restrict__ X0, const float* __restrict__ X1,
                             const float* __restrict__ X2,
                             bf16* __restrict__ O0, bf16* __restrict__ O1, bf16* __restrict__ O2,
                             int n4) {
    int z = blockIdx.z;
    const float* in = z == 0 ? X0 : (z == 1 ? X1 : X2);
    bf16* out = z == 0 ? O0 : (z == 1 ? O1 : O2);
    int idx = blockIdx.x * blockDim.x + threadIdx.x;
    int stride = gridDim.x * blockDim.x;
    for (int i = idx; i < n4; i += stride) {
        float4 v = reinterpret_cast<const float4*>(in)[i];
        reinterpret_cast<uint2*>(out)[i] = make_uint2(pack2bf(v.x, v.y), pack2bf(v.z, v.w));
    }
}

// ---------------- 1024x1024 fp32 -> bf16 transpose, four weights (z) ----------------
__global__ void transpose4_kernel(const float* __restrict__ W0, const float* __restrict__ W1,
                                  const float* __restrict__ W2, const float* __restrict__ W3,
                                  bf16* __restrict__ T0, bf16* __restrict__ T1,
                                  bf16* __restrict__ T2, bf16* __restrict__ T3) {
    int z = blockIdx.z;
    const float* W = z == 0 ? W0 : (z == 1 ? W1 : (z == 2 ? W2 : W3));
    bf16* WT = z == 0 ? T0 : (z == 1 ? T1 : (z == 2 ? T2 : T3));
    __shared__ float t[32][33];
    int bx = blockIdx.x * 32, by = blockIdx.y * 32;
    int x = threadIdx.x, y = threadIdx.y;
    #pragma unroll
    for (int i = 0; i < 4; ++i)
        t[y + 8*i][x] = W[(size_t)(by + y + 8*i) * 1024 + bx + x];
    __syncthreads();
    #pragma unroll
    for (int i = 0; i < 4; ++i)
        WT[(size_t)(bx + y + 8*i) * 1024 + by + x] = __float2bfloat16(t[x][y + 8*i]);
}

// ---------------- GEMM: C[4096,NTOT] = A[4096,1024] @ BT^T + bias ----------------
// m97 structure: 128xNTILE tile, BK=64, single-buffered LDS, global_load_lds w16,
// XOR-swizzled rows via pre-swizzled global src, two barriers per K-step.
// mode = mode_base+z: 0 bf16 out *log2e/sqrt2 | 1 bf16 | 2 bf16 -> Vt[b][h][dv][s] | 3 fp32
template<int NTILE>
__global__ __launch_bounds__(256, 3)
void gemm_bt(const bf16* __restrict__ A0, const bf16* __restrict__ A1, const bf16* __restrict__ A2,
             const bf16* __restrict__ B0, const bf16* __restrict__ B1, const bf16* __restrict__ B2,
             const float* __restrict__ bi0, const float* __restrict__ bi1, const float* __restrict__ bi2,
             void* __restrict__ O0, void* __restrict__ O1, void* __restrict__ O2,
             int mode_base)
{
    const int f = blockIdx.x;
    int x, y, z;
    if (NTILE == 128) {
        const int s = f >> 3;
        y = s & 7;
        const int t = (f & 7) + 8 * (s >> 3);
        x = t & 31; z = t >> 5;
    } else {
        const int s = f >> 3;
        y = s & 15;
        x = (f & 7) + 8 * (s >> 4);
        z = 0;
    }
    const bf16* A  = z == 0 ? A0 : (z == 1 ? A1 : A2);
    const bf16* BT = z == 0 ? B0 : (z == 1 ? B1 : B2);
    const float* bias = z == 0 ? bi0 : (z == 1 ? bi1 : bi2);
    void* Cout = z == 0 ? O0 : (z == 1 ? O1 : O2);
    const int mode = mode_base + z;

    constexpr int MF = (NTILE == 128) ? 4 : 2;
    __shared__ __align__(16) char Abuf[16384];
    __shared__ __align__(16) char Bbuf[NTILE * 128];
    const int tid = threadIdx.x;
    const int wave = tid >> 6, lane = tid & 63;
    const int g = lane >> 4, ln = lane & 15;
    const int m0 = x * 128, n0 = y * NTILE;
    const int wm = (NTILE == 128) ? (wave >> 1) * 64 : wave * 32;
    const int wn = (NTILE == 128) ? (wave & 1) * 64 : 0;
    const int lnsw = (ln & 7) << 4;

    f32x4 acc[MF][4] = {};

    for (int k0 = 0; k0 < 1024; k0 += 64) {
        __syncthreads();
        #pragma unroll
        for (int rd = 0; rd < 4; ++rd) {
            int row = rd * 32 + (tid >> 3);
            int src = ((tid & 7) * 16) ^ (((tid >> 3) & 7) << 4);
            gload_lds16((const char*)(A + (size_t)(m0 + row) * 1024 + k0) + src,
                        Abuf + rd * 4096 + tid * 16);
        }
        #pragma unroll
        for (int rd = 0; rd < NTILE / 32; ++rd) {
            int row = rd * 32 + (tid >> 3);
            int src = ((tid & 7) * 16) ^ (((tid >> 3) & 7) << 4);
            gload_lds16((const char*)(BT + (size_t)(n0 + row) * 1024 + k0) + src,
                        Bbuf + rd * 4096 + tid * 16);
        }
        __syncthreads();
        #pragma unroll
        for (int kk = 0; kk < 2; ++kk) {
            bf16x8 af[MF], bfr[4];
            #pragma unroll
            for (int mf = 0; mf < MF; ++mf)
                af[mf] = *(const bf16x8*)&Abuf[(wm + mf*16 + ln) * 128 + ((kk*64 + g*16) ^ lnsw)];
            #pragma unroll
            for (int nf = 0; nf < 4; ++nf)
                bfr[nf] = *(const bf16x8*)&Bbuf[(wn + nf*16 + ln) * 128 + ((kk*64 + g*16) ^ lnsw)];
            #pragma unroll
            for (int mf = 0; mf < MF; ++mf)
                #pragma unroll
                for (int nf = 0; nf < 4; ++nf)
                    acc[mf][nf] = __builtin_amdgcn_mfma_f32_16x16x32_bf16(af[mf], bfr[nf], acc[mf][nf], 0, 0, 0);
        }
    }

    const float scl = (mode == 0) ? (0.70710678118654752f * 1.44269504088896340f) : 1.0f;
    #pragma unroll
    for (int mf = 0; mf < MF; ++mf) {
        #pragma unroll
        for (int nf = 0; nf < 4; ++nf) {
            int col = n0 + wn + nf*16 + ln;
            float bv = bias[col];
            #pragma unroll
            for (int r = 0; r < 4; ++r) {
                int row = m0 + wm + mf*16 + g*4 + r;
                float v = (acc[mf][nf][r] + bv) * scl;
                if (mode == 0 || mode == 1) {
                    ((bf16*)Cout)[(size_t)row * 1024 + col] = __float2bfloat16(v);
                } else if (mode == 2) {
                    int b = row >> 11, ss = row & 2047;
                    int hh = col >> 6, dv = col & 63;
                    ((bf16*)Cout)[(((size_t)(b*16 + hh) * 64 + dv) << 11) + ss] = __float2bfloat16(v);
                } else {
                    ((float*)Cout)[(size_t)row * 1024 + col] = v;
                }
            }
        }
    }
}

// ---------------- flash attention, software-pipelined ----------------
// qh: [B*S][1024] bf16 pre-scaled by log2e/sqrt(2); kh: [B*S][1024] bf16;
// vt: [B][H][64][2048] bf16; aout: [B*S][1024] bf16.
// 128 q/block, 4 waves x 32 q, 32 tiles of 64 kv.
// PIPELINE: iter t issues QK(t) (MFMA) then SM(t-1)+PV(t-1) (VALU/TRANS then MFMA)
// -> QK(t)'s pipe drain hides under SM(t-1); PV(t-1) independent of QK(t).
// K double-buffered (16KB), V TRIPLE-buffered (24KB) since PV reads V one iter late.
// Scores ping-pong sacA/sacB (2x unroll, no runtime reg indexing).
__global__ __launch_bounds__(256, 2)
void attn_kernel(const bf16* __restrict__ qh, const bf16* __restrict__ kh,
                 const bf16* __restrict__ vt, bf16* __restrict__ aout)
{
    __shared__ __align__(16) bf16 Kls[2][64 * 64];
    __shared__ __align__(16) bf16 Vls[3][64 * 64];
    const int f = blockIdx.x;
    const int xcd = f & 7, s = f >> 3, i = s & 15, ghi = s >> 4;
    const int bh = xcd + 8 * ghi;
    const int b = bh >> 4, h = bh & 15;
    const int q0 = i * 128;

    const int tid = threadIdx.x;
    const int wave = tid >> 6, lane = tid & 63;
    const int g = lane >> 4, ln = lane & 15;
    const int srow = lane >> 3;
    const int scol = ((lane & 7) * 16) ^ ((srow & 7) << 4);
    const int lnsw = (ln & 7) << 4;

    const bf16* kbase = kh + (size_t)(b * 2048) * 1024 + h * 64;
    const bf16* vbase = vt + (size_t)bh * 64 * 2048;
    char* Kb = (char*)&Kls[0][0];
    char* Vb = (char*)&Vls[0][0];

    bf16x8 qf[2][2];
    #pragma unroll
    for (int nf = 0; nf < 2; ++nf) {
        const bf16* qrow = qh + (size_t)(b*2048 + q0 + wave*32 + nf*16 + ln) * 1024 + h*64;
        qf[nf][0] = *(const bf16x8*)(qrow + g*8);
        qf[nf][1] = *(const bf16x8*)(qrow + 32 + g*8);
    }

    // stage tile (64 kv): 4 loads/wave (2 K chunks + 2 V chunks)
    auto stageKV = [&](int kv0, int kbuf, int vbuf) {
        #pragma unroll
        for (int c2 = 0; c2 < 2; ++c2) {
            int c = wave * 2 + c2;
            int row = c * 8 + srow;
            gload_lds16((const char*)(kbase + (size_t)(kv0 + row) * 1024) + scol,
                        Kb + kbuf * 8192 + c * 1024);
            gload_lds16((const char*)(vbase + (size_t)row * 2048 + kv0) + scol,
                        Vb + vbuf * 8192 + c * 1024);
        }
    };

    f32x4 oacc[4][2] = {};
    f32x4 lacc[2] = {};
    f32x4 sacA[4][2], sacB[4][2];
    union PU { unsigned u[4]; bf16x8 v; };
    PU ones;
    ones.u[0] = ones.u[1] = ones.u[2] = ones.u[3] = 0x3F803F80u;  // bf16 1.0 x2

    int vS = 1, vC = 0, vP = 2;   // staged(t+1) / current(t) / prev(t-1) V buffers

    // SM(sacOld)->pf then PV into oacc/lacc, reading V at buffer vbuf
    auto SMPV = [&](f32x4 (&sac)[4][2], int vbuf) {
        PU pf[2][2];
        #pragma unroll
        for (int nf = 0; nf < 2; ++nf) {
            unsigned w[4][2];
            #pragma unroll
            for (int mf = 0; mf < 4; ++mf) {
                float e0 = fexp2(sac[mf][nf][0]);
                float e1 = fexp2(sac[mf][nf][1]);
                float e2 = fexp2(sac[mf][nf][2]);
                float e3 = fexp2(sac[mf][nf][3]);
                w[mf][0] = cvtpk(e0, e1);
                w[mf][1] = cvtpk(e2, e3);
            }
            #pragma unroll
            for (int kk = 0; kk < 2; ++kk) {
                #pragma unroll
                for (int rp = 0; rp < 2; ++rp) {
                    unsigned a = w[2*kk][rp], bb = w[2*kk + 1][rp];
                    pls32(a, bb);
                    pls16(a, bb);
                    pf[nf][kk].u[rp] = a;
                    pf[nf][kk].u[2 + rp] = bb;
                }
            }
        }
        const char* Vc = Vb + vbuf * 8192;
        __builtin_amdgcn_s_setprio(1);
        #pragma unroll
        for (int kk = 0; kk < 2; ++kk) {
            bf16x8 vf[4];
            #pragma unroll
            for (int mf = 0; mf < 4; ++mf)
                vf[mf] = *(const bf16x8*)(Vc + (mf*16 + ln) * 128 + ((kk*64 + g*16) ^ lnsw));
            #pragma unroll
            for (int nf = 0; nf < 2; ++nf)
                lacc[nf] = __builtin_amdgcn_mfma_f32_16x16x32_bf16(ones.v, pf[nf][kk].v, lacc[nf], 0, 0, 0);
            #pragma unroll
            for (int mf = 0; mf < 4; ++mf)
                #pragma unroll
                for (int nf = 0; nf < 2; ++nf)
                    oacc[mf][nf] = __builtin_amdgcn_mfma_f32_16x16x32_bf16(vf[mf], pf[nf][kk].v, oacc[mf][nf], 0, 0, 0);
        }
        __builtin_amdgcn_s_setprio(0);
    };

    // one pipeline stage: stage(t+1) | wait+barrier | QK(t)->sacNew | SM/PV(t-1) | barrier
    auto iter = [&](int t, f32x4 (&sacNew)[4][2], f32x4 (&sacOld)[4][2], bool doPrev) {
        if (t < 31) {
            stageKV((t + 1) * 64, (t + 1) & 1, vS);
            asm volatile("s_waitcnt vmcnt(4)\n\ts_barrier" ::: "memory");
        } else {
            asm volatile("s_waitcnt vmcnt(0)\n\ts_barrier" ::: "memory");
        }
        __builtin_amdgcn_sched_barrier(0);

        const char* Kc = Kb + (t & 1) * 8192;
        #pragma unroll
        for (int mf = 0; mf < 4; ++mf)
            #pragma unroll
            for (int nf = 0; nf < 2; ++nf)
                sacNew[mf][nf] = f32x4{0.f, 0.f, 0.f, 0.f};
        __builtin_amdgcn_s_setprio(1);
        #pragma unroll
        for (int kk = 0; kk < 2; ++kk) {
            bf16x8 kf[4];
            #pragma unroll
            for (int mf = 0; mf < 4; ++mf)
                kf[mf] = *(const bf16x8*)(Kc + (mf*16 + ln) * 128 + ((kk*64 + g*16) ^ lnsw));
            #pragma unroll
            for (int mf = 0; mf < 4; ++mf)
                #pragma unroll
                for (int nf = 0; nf < 2; ++nf)
                    sacNew[mf][nf] = __builtin_amdgcn_mfma_f32_16x16x32_bf16(kf[mf], qf[nf][kk], sacNew[mf][nf], 0, 0, 0);
        }
        __builtin_amdgcn_s_setprio(0);
        __builtin_amdgcn_sched_barrier(0);   // pin: all QK issued before SM (drain hides under SM)

        if (doPrev)
            SMPV(sacOld, vP);

        asm volatile("s_waitcnt lgkmcnt(0)\n\ts_barrier" ::: "memory");
        int t0 = vP; (void)t0;
        vP = vC; vC = vS; vS = (vS == 2) ? 0 : vS + 1;
    };

    stageKV(0, 0, 0);
    iter(0, sacA, sacB, false);
    for (int p = 0; p < 15; ++p) {
        iter(2 * p + 1, sacB, sacA, true);
        iter(2 * p + 2, sacA, sacB, true);
    }
    iter(31, sacB, sacA, true);
    SMPV(sacB, vP);    // drain: SM+PV for tile 31 (vP == 31%3 after final rotation)

    #pragma unroll
    for (int nf = 0; nf < 2; ++nf) {
        float inv = 1.0f / lacc[nf][0];
        int q = q0 + wave*32 + nf*16 + ln;
        bf16* orow = aout + (size_t)(b*2048 + q) * 1024 + h * 64;
        #pragma unroll
        for (int mf = 0; mf < 4; ++mf) {
            *(uint2*)(orow + mf*16 + g*4) = make_uint2(
                pack2bf(oacc[mf][nf][0] * inv, oacc[mf][nf][1] * inv),
                pack2bf(oacc[mf][nf][2] * inv, oacc[mf][nf][3] * inv));
        }
    }
}

// ---------------- host ----------------
extern "C" void kernel_launch(void* const* d_in, const int* in_sizes, int n_in,
                              void* d_out, int out_size, void* d_ws, size_t ws_size,
                              hipStream_t stream)
{
    const float* Q  = (const float*)d_in[0];
    const float* K  = (const float*)d_in[1];
    const float* V  = (const float*)d_in[2];
    const float* Wq = (const float*)d_in[3];
    const float* bq = (const float*)d_in[4];
    const float* Wk = (const float*)d_in[5];
    const float* bk = (const float*)d_in[6];
    const float* Wv = (const float*)d_in[7];
    const float* bv = (const float*)d_in[8];
    const float* Wo = (const float*)d_in[9];
    const float* bo = (const float*)d_in[10];

    char* ws = (char*)d_ws;
    const size_t MB = 1024 * 1024;
    bf16* Qbf  = (bf16*)(ws + 0);
    bf16* Kbf  = (bf16*)(ws + 8*MB);
    bf16* Vbf  = (bf16*)(ws + 16*MB);
    bf16* WqT  = (bf16*)(ws + 24*MB);
    bf16* WkT  = (bf16*)(ws + 26*MB);
    bf16* WvT  = (bf16*)(ws + 28*MB);
    bf16* WoT  = (bf16*)(ws + 30*MB);
    bf16* qhp  = (bf16*)(ws + 32*MB);
    bf16* khp  = (bf16*)(ws + 40*MB);
    bf16* vtp  = (bf16*)(ws + 48*MB);
    bf16* aout = (bf16*)(ws + 0);      // alias Qbf (dead after projections)

    const int n4 = (2 * 2048 * 1024) / 4;
    conv3_kernel<<<dim3(512, 1, 3), 256, 0, stream>>>(Q, K, V, Qbf, Kbf, Vbf, n4);

    transpose4_kernel<<<dim3(32, 32, 4), dim3(32, 8), 0, stream>>>(Wq, Wk, Wv, Wo, WqT, WkT, WvT, WoT);

    gemm_bt<128><<<768, 256, 0, stream>>>(Qbf, Kbf, Vbf, WqT, WkT, WvT,
                                          bq, bk, bv, qhp, khp, vtp, 0);

    attn_kernel<<<512, 256, 0, stream>>>(qhp, khp, vtp, aout);

    gemm_bt<64><<<512, 256, 0, stream>>>(aout, aout, aout, WoT, WoT, WoT,
                                         bo, bo, bo, d_out, d_out, d_out, 3);
}

// Round 12
// 114.920 us; speedup vs baseline: 1.0546x; 1.0197x over previous
//
#include <hip/hip_runtime.h>
#include <hip/hip_bf16.h>

// MHA layer B=2, S=2048, DM=1024, H=16, DK=DV=64 on gfx950.
// weight transposes -> 3 proj GEMMs (fp32 A staged direct via global_load_lds,
// (row&15) swizzle, conv fused) -> flash attention (wave = 64q x 64kv-half,
// halved LDS-read amplification, in-LDS pair combine) -> out GEMM (128x64).

using bf16 = __hip_bfloat16;
typedef __attribute__((ext_vector_type(4))) float f32x4;
typedef __attribute__((ext_vector_type(8))) short bf16x8;

__device__ __forceinline__ void gload_lds16(const void* gsrc, void* ldst) {
    __builtin_amdgcn_global_load_lds(
        (const __attribute__((address_space(1))) void*)gsrc,
        (__attribute__((address_space(3))) void*)ldst,
        16, 0, 0);
}

__device__ __forceinline__ float fexp2(float x) {
    float r; asm("v_exp_f32 %0, %1" : "=v"(r) : "v"(x)); return r;
}

__device__ __forceinline__ unsigned cvtpk(float a, float b) {
    unsigned d; asm("v_cvt_pk_bf16_f32 %0, %1, %2" : "=v"(d) : "v"(a), "v"(b));
    return d;
}

__device__ __forceinline__ void pls32(unsigned &a, unsigned &b) {
    asm("v_permlane32_swap_b32 %0, %1" : "+v"(a), "+v"(b));
}
__device__ __forceinline__ void pls16(unsigned &a, unsigned &b) {
    asm("v_permlane16_swap_b32 %0, %1" : "+v"(a), "+v"(b));
}

__device__ __forceinline__ unsigned pack2bf(float a, float b) {
    unsigned short ua = __builtin_bit_cast(unsigned short, __float2bfloat16(a));
    unsigned short ub = __builtin_bit_cast(unsigned short, __float2bfloat16(b));
    return (unsigned)ua | ((unsigned)ub << 16);
}

// ---------------- 1024x1024 fp32 -> bf16 transpose, four weights (z) ----------------
__global__ void transpose4_kernel(const float* __restrict__ W0, const float* __restrict__ W1,
                                  const float* __restrict__ W2, const float* __restrict__ W3,
                                  bf16* __restrict__ T0, bf16* __restrict__ T1,
                                  bf16* __restrict__ T2, bf16* __restrict__ T3) {
    int z = blockIdx.z;
    const float* W = z == 0 ? W0 : (z == 1 ? W1 : (z == 2 ? W2 : W3));
    bf16* WT = z == 0 ? T0 : (z == 1 ? T1 : (z == 2 ? T2 : T3));
    __shared__ float t[32][33];
    int bx = blockIdx.x * 32, by = blockIdx.y * 32;
    int x = threadIdx.x, y = threadIdx.y;
    #pragma unroll
    for (int i = 0; i < 4; ++i)
        t[y + 8*i][x] = W[(size_t)(by + y + 8*i) * 1024 + bx + x];
    __syncthreads();
    #pragma unroll
    for (int i = 0; i < 4; ++i)
        WT[(size_t)(bx + y + 8*i) * 1024 + by + x] = __float2bfloat16(t[x][y + 8*i]);
}

// ---------------- GEMM: C[4096,NTOT] = A[4096,1024] @ BT^T + bias ----------------
// m97 structure, BK=64, single-buffered, global_load_lds w16, swizzled rows.
// AF32: A fp32 staged directly (256B rows, (row&15)<<4 swizzle), converted in the
// fragment path via v_cvt_pk_bf16_f32 (fuses the fp32->bf16 conv pass).
// mode = mode_base+z: 0 bf16 out *log2e/sqrt2 | 1 bf16 | 2 bf16 -> Vt[b][h][dv][s] | 3 fp32
template<int NTILE, bool AF32>
__global__ __launch_bounds__(256, 3)
void gemm_bt(const void* __restrict__ A0, const void* __restrict__ A1, const void* __restrict__ A2,
             const bf16* __restrict__ B0, const bf16* __restrict__ B1, const bf16* __restrict__ B2,
             const float* __restrict__ bi0, const float* __restrict__ bi1, const float* __restrict__ bi2,
             void* __restrict__ O0, void* __restrict__ O1, void* __restrict__ O2,
             int mode_base)
{
    const int f = blockIdx.x;
    int x, y, z;
    if (NTILE == 128) {
        const int s = f >> 3;
        y = s & 7;
        const int t = (f & 7) + 8 * (s >> 3);
        x = t & 31; z = t >> 5;
    } else {
        const int s = f >> 3;
        y = s & 15;
        x = (f & 7) + 8 * (s >> 4);
        z = 0;
    }
    const void* Av = z == 0 ? A0 : (z == 1 ? A1 : A2);
    const bf16* BT = z == 0 ? B0 : (z == 1 ? B1 : B2);
    const float* bias = z == 0 ? bi0 : (z == 1 ? bi1 : bi2);
    void* Cout = z == 0 ? O0 : (z == 1 ? O1 : O2);
    const int mode = mode_base + z;

    constexpr int MF = (NTILE == 128) ? 4 : 2;
    __shared__ __align__(16) char Abuf[AF32 ? 32768 : 16384];
    __shared__ __align__(16) char Bbuf[NTILE * 128];
    const int tid = threadIdx.x;
    const int wave = tid >> 6, lane = tid & 63;
    const int g = lane >> 4, ln = lane & 15;
    const int m0 = x * 128, n0 = y * NTILE;
    const int wm = (NTILE == 128) ? (wave >> 1) * 64 : wave * 32;
    const int wn = (NTILE == 128) ? (wave & 1) * 64 : 0;
    const int lnsw = (ln & 7) << 4;

    f32x4 acc[MF][4] = {};

    for (int k0 = 0; k0 < 1024; k0 += 64) {
        __syncthreads();
        #pragma unroll
        for (int rd = 0; rd < NTILE / 32; ++rd) {
            int row = rd * 32 + (tid >> 3);
            int src = ((tid & 7) * 16) ^ (((tid >> 3) & 7) << 4);
            gload_lds16((const char*)(BT + (size_t)(n0 + row) * 1024 + k0) + src,
                        Bbuf + rd * 4096 + tid * 16);
        }
        if (AF32) {
            // A fp32: 128 rows x 256B, swizzle col16 ^= (row&15)
            #pragma unroll
            for (int rd = 0; rd < 8; ++rd) {
                int row = rd * 16 + (tid >> 4);
                int src = ((tid & 15) * 16) ^ ((row & 15) << 4);
                gload_lds16((const char*)((const float*)Av + (size_t)(m0 + row) * 1024 + k0) + src,
                            Abuf + rd * 4096 + tid * 16);
            }
        } else {
            #pragma unroll
            for (int rd = 0; rd < 4; ++rd) {
                int row = rd * 32 + (tid >> 3);
                int src = ((tid & 7) * 16) ^ (((tid >> 3) & 7) << 4);
                gload_lds16((const char*)((const bf16*)Av + (size_t)(m0 + row) * 1024 + k0) + src,
                            Abuf + rd * 4096 + tid * 16);
            }
        }
        __syncthreads();
        #pragma unroll
        for (int kk = 0; kk < 2; ++kk) {
            bf16x8 af[MF], bfr[4];
            #pragma unroll
            for (int mf = 0; mf < MF; ++mf) {
                int row = wm + mf * 16 + ln;
                if (AF32) {
                    int c0 = kk * 128 + g * 32;
                    int sw = (row & 15) << 4;
                    f32x4 v0 = *(const f32x4*)(Abuf + row * 256 + (c0 ^ sw));
                    f32x4 v1 = *(const f32x4*)(Abuf + row * 256 + ((c0 + 16) ^ sw));
                    union { unsigned u[4]; bf16x8 v; } afu;
                    afu.u[0] = cvtpk(v0[0], v0[1]); afu.u[1] = cvtpk(v0[2], v0[3]);
                    afu.u[2] = cvtpk(v1[0], v1[1]); afu.u[3] = cvtpk(v1[2], v1[3]);
                    af[mf] = afu.v;
                } else {
                    af[mf] = *(const bf16x8*)&Abuf[row * 128 + ((kk*64 + g*16) ^ ((row & 7) << 4))];
                }
            }
            #pragma unroll
            for (int nf = 0; nf < 4; ++nf) {
                int row = wn + nf * 16 + ln;
                bfr[nf] = *(const bf16x8*)&Bbuf[row * 128 + ((kk*64 + g*16) ^ ((row & 7) << 4))];
            }
            #pragma unroll
            for (int mf = 0; mf < MF; ++mf)
                #pragma unroll
                for (int nf = 0; nf < 4; ++nf)
                    acc[mf][nf] = __builtin_amdgcn_mfma_f32_16x16x32_bf16(af[mf], bfr[nf], acc[mf][nf], 0, 0, 0);
        }
    }

    const float scl = (mode == 0) ? (0.70710678118654752f * 1.44269504088896340f) : 1.0f;
    #pragma unroll
    for (int mf = 0; mf < MF; ++mf) {
        #pragma unroll
        for (int nf = 0; nf < 4; ++nf) {
            int col = n0 + wn + nf*16 + ln;
            float bv = bias[col];
            #pragma unroll
            for (int r = 0; r < 4; ++r) {
                int row = m0 + wm + mf*16 + g*4 + r;
                float v = (acc[mf][nf][r] + bv) * scl;
                if (mode == 0 || mode == 1) {
                    ((bf16*)Cout)[(size_t)row * 1024 + col] = __float2bfloat16(v);
                } else if (mode == 2) {
                    int b = row >> 11, ss = row & 2047;
                    int hh = col >> 6, dv = col & 63;
                    ((bf16*)Cout)[(((size_t)(b*16 + hh) * 64 + dv) << 11) + ss] = __float2bfloat16(v);
                } else {
                    ((float*)Cout)[(size_t)row * 1024 + col] = v;
                }
            }
        }
    }
}

// ---------------- flash attention: wave = (q-half, kv-half) ----------------
// qh_: [B*S][1024] bf16 pre-scaled by log2e/sqrt(2); kh: [B*S][1024] bf16;
// vt: [B][H][64][2048] bf16; aout: [B*S][1024] bf16.
// Block: 128 q x 128 kv/iter (16 iters), 4 waves: wave=(qh<<1|kvh), each 64q x 64kv.
// K: [128][128B] swz (row&7)<<4; V: [64dv][256B] swz col16^=(row&15).
// Doubles per-wave reuse -> LDS-read amplification halves vs 32q waves.
// kv-halves combined once at end through dead K-LDS. lsum in VALU.
__global__ __launch_bounds__(256, 2)
void attn_kernel(const bf16* __restrict__ qh_, const bf16* __restrict__ kh,
                 const bf16* __restrict__ vt, bf16* __restrict__ aout)
{
    __shared__ __align__(16) bf16 Kls[2][128 * 64];
    __shared__ __align__(16) bf16 Vls[2][64 * 128];
    const int f = blockIdx.x;
    const int xcd = f & 7, s = f >> 3, i = s & 15, ghi = s >> 4;
    const int bh = xcd + 8 * ghi;
    const int b = bh >> 4, h = bh & 15;
    const int q0 = i * 128;

    const int tid = threadIdx.x;
    const int wave = tid >> 6, lane = tid & 63;
    const int qh = wave >> 1, kvh = wave & 1;
    const int g = lane >> 4, ln = lane & 15;
    const int srow = lane >> 3;
    const int scol = ((lane & 7) * 16) ^ ((srow & 7) << 4);
    const int lnsw = (ln & 7) << 4;
    const int vrow_in = lane >> 4, vcol16 = lane & 15;

    const bf16* kbase = kh + (size_t)(b * 2048) * 1024 + h * 64;
    const bf16* vbase = vt + (size_t)bh * 64 * 2048;
    char* Kb = (char*)&Kls[0][0];
    char* Vb = (char*)&Vls[0][0];

    // Q fragments: 64 q rows per wave
    bf16x8 qf[4][2];
    #pragma unroll
    for (int nf = 0; nf < 4; ++nf) {
        const bf16* qrow = qh_ + (size_t)(b*2048 + q0 + qh*64 + nf*16 + ln) * 1024 + h*64;
        qf[nf][0] = *(const bf16x8*)(qrow + g*8);
        qf[nf][1] = *(const bf16x8*)(qrow + 32 + g*8);
    }

    // stage 128-kv tile: K 16KB (16 chunks of 8 rows), V 16KB (16 chunks of 4x256B rows)
    auto stageKV = [&](int kv0, int buf) {
        #pragma unroll
        for (int c2 = 0; c2 < 4; ++c2) {
            int c = wave * 4 + c2;
            int krow = c * 8 + srow;
            gload_lds16((const char*)(kbase + (size_t)(kv0 + krow) * 1024) + scol,
                        Kb + buf * 16384 + c * 1024);
        }
        #pragma unroll
        for (int c2 = 0; c2 < 4; ++c2) {
            int c = wave * 4 + c2;
            int vrow = c * 4 + vrow_in;
            int sc16 = vcol16 ^ (vrow & 15);
            gload_lds16((const char*)(vbase + (size_t)vrow * 2048 + kv0) + sc16 * 16,
                        Vb + buf * 16384 + c * 1024);
        }
    };

    stageKV(0, 0);

    f32x4 oacc[4][4] = {};
    float lsum[4] = {0.f, 0.f, 0.f, 0.f};
    union PU { unsigned u[4]; bf16x8 v; };

    for (int t = 0; t < 16; ++t) {
        const int cur = t & 1;
        if (t < 15) {
            stageKV((t + 1) * 128, cur ^ 1);
            asm volatile("s_waitcnt vmcnt(8)\n\ts_barrier" ::: "memory");
        } else {
            asm volatile("s_waitcnt vmcnt(0)\n\ts_barrier" ::: "memory");
        }
        __builtin_amdgcn_sched_barrier(0);

        const char* Kc = Kb + cur * 16384;
        const char* Vc = Vb + cur * 16384;

        // QK: S^T rows = local kv (wave's 64-half), cols = q (64 over 4 nf)
        f32x4 sac[4][4] = {};
        __builtin_amdgcn_s_setprio(1);
        #pragma unroll
        for (int kk = 0; kk < 2; ++kk) {
            bf16x8 kf[4];
            #pragma unroll
            for (int mf = 0; mf < 4; ++mf) {
                int row = kvh*64 + mf*16 + ln;
                kf[mf] = *(const bf16x8*)(Kc + row * 128 + ((kk*64 + g*16) ^ lnsw));
            }
            #pragma unroll
            for (int mf = 0; mf < 4; ++mf)
                #pragma unroll
                for (int nf = 0; nf < 4; ++nf)
                    sac[mf][nf] = __builtin_amdgcn_mfma_f32_16x16x32_bf16(kf[mf], qf[nf][kk], sac[mf][nf], 0, 0, 0);
        }
        __builtin_amdgcn_s_setprio(0);
        __builtin_amdgcn_sched_barrier(0);

        // SM: P = exp2(s), lsum += rows, pack, butterfly -> pf[nf][kk]
        PU pf[4][2];
        #pragma unroll
        for (int nf = 0; nf < 4; ++nf) {
            unsigned w[4][2];
            #pragma unroll
            for (int mf = 0; mf < 4; ++mf) {
                float e0 = fexp2(sac[mf][nf][0]);
                float e1 = fexp2(sac[mf][nf][1]);
                float e2 = fexp2(sac[mf][nf][2]);
                float e3 = fexp2(sac[mf][nf][3]);
                lsum[nf] += (e0 + e1) + (e2 + e3);
                w[mf][0] = cvtpk(e0, e1);
                w[mf][1] = cvtpk(e2, e3);
            }
            #pragma unroll
            for (int kk = 0; kk < 2; ++kk) {
                #pragma unroll
                for (int rp = 0; rp < 2; ++rp) {
                    unsigned a = w[2*kk][rp], bb = w[2*kk + 1][rp];
                    pls32(a, bb);
                    pls16(a, bb);
                    pf[nf][kk].u[rp] = a;
                    pf[nf][kk].u[2 + rp] = bb;
                }
            }
        }

        // PV: O^T[64dv][64q] += V^T(wave's kv-half) * P
        __builtin_amdgcn_s_setprio(1);
        #pragma unroll
        for (int kk = 0; kk < 2; ++kk) {
            bf16x8 vf[4];
            #pragma unroll
            for (int mf = 0; mf < 4; ++mf) {
                int row = mf*16 + ln;
                vf[mf] = *(const bf16x8*)(Vc + row * 256 + (((kvh*8 + kk*4 + g) ^ ln) << 4));
            }
            #pragma unroll
            for (int mf = 0; mf < 4; ++mf)
                #pragma unroll
                for (int nf = 0; nf < 4; ++nf)
                    oacc[mf][nf] = __builtin_amdgcn_mfma_f32_16x16x32_bf16(vf[mf], pf[nf][kk].v, oacc[mf][nf], 0, 0, 0);
        }
        __builtin_amdgcn_s_setprio(0);
        __builtin_amdgcn_sched_barrier(0);
        asm volatile("s_waitcnt lgkmcnt(0)\n\ts_barrier" ::: "memory");
    }

    // reduce lsum over g (kv spread within wave), then combine kv-halves via LDS
    #pragma unroll
    for (int nf = 0; nf < 4; ++nf) {
        float l = lsum[nf];
        l += __shfl_xor(l, 16);
        l += __shfl_xor(l, 32);
        lsum[nf] = l;
    }
    __syncthreads();
    float* Lb = (float*)Vb;
    if (kvh == 1) {
        #pragma unroll
        for (int mf = 0; mf < 4; ++mf)
            #pragma unroll
            for (int nf = 0; nf < 4; ++nf)
                *(f32x4*)(Kb + qh * 16384 + (mf*4 + nf) * 1024 + lane * 16) = oacc[mf][nf];
        #pragma unroll
        for (int nf = 0; nf < 4; ++nf)
            Lb[qh * 256 + nf * 64 + lane] = lsum[nf];
    }
    __syncthreads();
    if (kvh == 0) {
        #pragma unroll
        for (int nf = 0; nf < 4; ++nf) {
            float inv = 1.0f / (lsum[nf] + Lb[qh * 256 + nf * 64 + lane]);
            int q = q0 + qh*64 + nf*16 + ln;
            bf16* orow = aout + (size_t)(b*2048 + q) * 1024 + h * 64;
            #pragma unroll
            for (int mf = 0; mf < 4; ++mf) {
                f32x4 o2 = *(const f32x4*)(Kb + qh * 16384 + (mf*4 + nf) * 1024 + lane * 16);
                float v0 = (oacc[mf][nf][0] + o2[0]) * inv;
                float v1 = (oacc[mf][nf][1] + o2[1]) * inv;
                float v2 = (oacc[mf][nf][2] + o2[2]) * inv;
                float v3 = (oacc[mf][nf][3] + o2[3]) * inv;
                *(uint2*)(orow + mf*16 + g*4) = make_uint2(pack2bf(v0, v1), pack2bf(v2, v3));
            }
        }
    }
}

// ---------------- host ----------------
extern "C" void kernel_launch(void* const* d_in, const int* in_sizes, int n_in,
                              void* d_out, int out_size, void* d_ws, size_t ws_size,
                              hipStream_t stream)
{
    const float* Q  = (const float*)d_in[0];
    const float* K  = (const float*)d_in[1];
    const float* V  = (const float*)d_in[2];
    const float* Wq = (const float*)d_in[3];
    const float* bq = (const float*)d_in[4];
    const float* Wk = (const float*)d_in[5];
    const float* bk = (const float*)d_in[6];
    const float* Wv = (const float*)d_in[7];
    const float* bv = (const float*)d_in[8];
    const float* Wo = (const float*)d_in[9];
    const float* bo = (const float*)d_in[10];

    char* ws = (char*)d_ws;
    const size_t MB = 1024 * 1024;
    bf16* WqT  = (bf16*)(ws + 24*MB);
    bf16* WkT  = (bf16*)(ws + 26*MB);
    bf16* WvT  = (bf16*)(ws + 28*MB);
    bf16* WoT  = (bf16*)(ws + 30*MB);
    bf16* qhp  = (bf16*)(ws + 32*MB);
    bf16* khp  = (bf16*)(ws + 40*MB);
    bf16* vtp  = (bf16*)(ws + 48*MB);
    bf16* aout = (bf16*)(ws + 0);

    transpose4_kernel<<<dim3(32, 32, 4), dim3(32, 8), 0, stream>>>(Wq, Wk, Wv, Wo, WqT, WkT, WvT, WoT);

    // 3 projection GEMMs, fp32 A direct (conv fused), A-tile XCD-grouped
    gemm_bt<128, true><<<768, 256, 0, stream>>>(Q, K, V, WqT, WkT, WvT,
                                                bq, bk, bv, qhp, khp, vtp, 0);

    attn_kernel<<<512, 256, 0, stream>>>(qhp, khp, vtp, aout);

    gemm_bt<64, false><<<512, 256, 0, stream>>>(aout, aout, aout, WoT, WoT, WoT,
                                                bo, bo, bo, d_out, d_out, d_out, 3);
}